// Round 14
// baseline (316.312 us; speedup 1.0000x reference)
//
#include <hip/hip_runtime.h>
#include <math.h>

#define B_ 32
#define T_ 128
#define H_ 768
#define N_ 1024
#define M_ 131072
#define DK 128
#define DV 512
#define NROWS 512
#define VPR 256
#define KTOP 32
#define EPS2 1.2f   // 2.7x the 2-sided hard error bound of 1-pass bf16 scoring
#define CCAP 96

typedef __attribute__((ext_vector_type(8))) short short8v;
typedef __attribute__((ext_vector_type(4))) float f32x4;

// ---- workspace layout (bytes) ----
#define WS_QF64   ((size_t)0)
#define WS_QHI    (WS_QF64 + (size_t)N_*DK*8)
#define WS_RMAX1  (WS_QHI + (size_t)N_*DK*2)
#define WS_RMAX2  (WS_RMAX1 + (size_t)N_*NROWS*4)
#define WS_RMAX3  (WS_RMAX2 + (size_t)N_*NROWS*4)
#define WS_POOLED (WS_RMAX3 + (size_t)N_*NROWS*4)
#define WS_DELTA  (WS_POOLED + (size_t)N_*DV*4)
#define WS_KHI    (WS_DELTA + (size_t)B_*T_*H_*4)
// total ~54 MB

__device__ __forceinline__ unsigned short bf16_rn(float x) {
  unsigned u = __float_as_uint(x);
  unsigned r = u + 0x7FFFu + ((u >> 16) & 1u);
  return (unsigned short)(r >> 16);
}

__device__ __forceinline__ void gload16(const void* g, void* l) {
  __builtin_amdgcn_global_load_lds(
      (const __attribute__((address_space(1))) void*)g,
      (__attribute__((address_space(3))) void*)l, 16, 0, 0);
}

// top-3 insert: 5 ops, exact (values are distinct via packed index bits)
__device__ __forceinline__ void ins3(float p, float& v1, float& v2, float& v3) {
  float m1 = fminf(v1, p);
  v1 = fmaxf(v1, p);
  float m2 = fminf(v2, m1);
  v2 = fmaxf(v2, m1);
  v3 = fmaxf(v3, m2);
}

// ---------------------------------------------------------------------------
// Kernel Z: fast zero-fill for delta.
// ---------------------------------------------------------------------------
__global__ __launch_bounds__(256) void k_zero(float4* __restrict__ p) {
  p[(size_t)blockIdx.x * 256 + threadIdx.x] = (float4){0.f, 0.f, 0.f, 0.f};
}

// ---------------------------------------------------------------------------
// Kernel 0: round keys to bf16 (hi only) ONCE, stored in the swizzled
// LDS-linear image: short index = row*32768 + kir*128 + (gt^(kir&15))*8 + d&7
// ---------------------------------------------------------------------------
__global__ __launch_bounds__(256) void k_split(
    const float* __restrict__ keys, unsigned short* __restrict__ khi) {
  int t = threadIdx.x;
  int key = blockIdx.x * 16 + (t >> 4);
  int gt = t & 15;  // dim granule (8 dims)
  const float* src = keys + (size_t)key * DK + gt * 8;
  float4 f0 = *(const float4*)(src);
  float4 f1 = *(const float4*)(src + 4);
  float f[8] = {f0.x, f0.y, f0.z, f0.w, f1.x, f1.y, f1.z, f1.w};
  unsigned h[8];
#pragma unroll
  for (int i = 0; i < 8; ++i) h[i] = bf16_rn(f[i]);
  int kir = key & 255, row = key >> 8;
  int g = gt ^ (kir & 15);
  size_t base = (size_t)row * 32768 + (size_t)kir * 128 + g * 8;
  uint4 uh = {h[0] | (h[1] << 16), h[2] | (h[3] << 16),
              h[4] | (h[5] << 16), h[6] | (h[7] << 16)};
  *(uint4*)(khi + base) = uh;
}

// ---------------------------------------------------------------------------
// Kernel 1: queries (f64 acc), 4 mentions per block (qw reuse x4).
// Writes qf64 + fragment-ordered bf16 hi pack.
// ---------------------------------------------------------------------------
__global__ __launch_bounds__(512) void k_queries(
    const float* __restrict__ enc, const int* __restrict__ mbp,
    const int* __restrict__ msp, const int* __restrict__ mep,
    const float* __restrict__ qw, const float* __restrict__ qb,
    double* __restrict__ qf64, unsigned short* __restrict__ qhi) {
  int g = blockIdx.x, t = threadIdx.x;
  int d = t & 127, qq = t >> 7;   // quarter 0..3
  __shared__ float se[4][H_], ee[4][H_];
  __shared__ double part[4][512];
#pragma unroll
  for (int mm = 0; mm < 4; ++mm) {
    int m = g * 4 + mm;
    int b = mbp[m], s = msp[m], e = mep[m];
    const float* rs = enc + ((size_t)(b * T_ + s)) * H_;
    const float* re = enc + ((size_t)(b * T_ + e)) * H_;
    for (int h = t; h < H_; h += 512) { se[mm][h] = rs[h]; ee[mm][h] = re[h]; }
  }
  __syncthreads();
  int h0 = (qq & 1) * 384;
  int wbase = (qq >> 1) * H_ + h0;
  double acc0 = 0, acc1 = 0, acc2 = 0, acc3 = 0;
  if (qq < 2) {
    for (int h = 0; h < 384; ++h) {
      double w = (double)qw[(size_t)(wbase + h) * DK + d];
      acc0 += (double)se[0][h0 + h] * w; acc1 += (double)se[1][h0 + h] * w;
      acc2 += (double)se[2][h0 + h] * w; acc3 += (double)se[3][h0 + h] * w;
    }
  } else {
    for (int h = 0; h < 384; ++h) {
      double w = (double)qw[(size_t)(wbase + h) * DK + d];
      acc0 += (double)ee[0][h0 + h] * w; acc1 += (double)ee[1][h0 + h] * w;
      acc2 += (double)ee[2][h0 + h] * w; acc3 += (double)ee[3][h0 + h] * w;
    }
  }
  part[0][t] = acc0; part[1][t] = acc1; part[2][t] = acc2; part[3][t] = acc3;
  __syncthreads();
  {
    int mm = t >> 7, dd = t & 127;
    int m = g * 4 + mm;
    double v = (double)qb[dd] + part[mm][dd] + part[mm][dd + 128] +
               part[mm][dd + 256] + part[mm][dd + 384];
    qf64[(size_t)m * DK + dd] = v;
    unsigned hv = bf16_rn((float)v);
    int mtg = m >> 4, r16 = m & 15, ks = dd >> 5, sub = (dd >> 3) & 3;
    size_t idx = ((size_t)(mtg * 4 + ks) * 64 + sub * 16 + r16) * 8 + (dd & 7);
    qhi[idx] = (unsigned short)hv;
  }
}

// ---------------------------------------------------------------------------
// Kernel 2: 1-pass bf16 MFMA scoring (qh*kh; hard error <=0.45, typ 0.03)
// + per-row TOP-3 (index packed in low 8 mantissa bits). 512 thr = 8 waves
// (4 mg x 2 kg), mt=2; tile 128m x 256k; 32-key chunks; 4 LDS buffers staged
// 3 ahead via global_load_lds (1 gload16/wave/chunk), counted s_waitcnt
// vmcnt(2) + raw s_barrier, setprio around the MFMA cluster.
// Output [row][mention], XCD row-grouped grid.
// NOTE (round 14): launched TWICE as a timing instrument - pure function of
// (khi,qhi), second launch writes identical values; delta vs round 13 total
// measures T(k_score) directly.
// ---------------------------------------------------------------------------
__global__ __launch_bounds__(512, 4) void k_score(
    const unsigned short* __restrict__ khi,
    const unsigned short* __restrict__ qhi,
    float* __restrict__ rmax1, float* __restrict__ rmax2,
    float* __restrict__ rmax3) {
  __shared__ unsigned short klds[4][32 * DK];     // 4 x 8 KB = 32 KB
  __shared__ float mbuf[128][6];                  // 3 KB
  int id = blockIdx.x;
  int row = (id & 7) * 64 + (id >> 6);   // a row's 8 Q-blocks on one XCD
  int Q = (id >> 3) & 7;     // 8 mention-tiles of 128
  int tid = threadIdx.x;
  int lane = tid & 63, wave = tid >> 6;
  int mg = wave >> 1, kg = wave & 1;
  int l15 = lane & 15, l4 = lane >> 4;

  const char* srcH = (const char*)khi + (size_t)row * 65536;

  // stage chunk c (32 keys = 8KB); each wave copies 1KB with one gload16.
  auto stage = [&](int c, int buf) {
    int off = wave * 1024;                        // wave-uniform LDS offset
    gload16(srcH + c * 8192 + off + lane * 16, (char*)&klds[buf][0] + off);
  };

  // q hi-fragments hoisted once: 2 mention-subtiles x 4 ks = 32 VGPR
  short8v ah[4][2];
#pragma unroll
  for (int ks = 0; ks < 4; ++ks)
#pragma unroll
    for (int mt = 0; mt < 2; ++mt) {
      int mtg = Q * 8 + mg * 2 + mt;
      size_t aoff = ((size_t)(mtg * 4 + ks) * 64 + lane) * 8;
      ah[ks][mt] = *(const short8v*)(qhi + aoff);
    }

  float rv1[2][4], rv2[2][4], rv3[2][4];
#pragma unroll
  for (int mt = 0; mt < 2; ++mt)
#pragma unroll
    for (int r = 0; r < 4; ++r) {
      rv1[mt][r] = -INFINITY; rv2[mt][r] = -INFINITY; rv3[mt][r] = -INFINITY;
    }

  stage(0, 0);
  stage(1, 1);
  stage(2, 2);

#pragma unroll
  for (int c = 0; c < 8; ++c) {
    // counted wait: chunk c landed; up to 2 younger stages stay in flight.
    if (c < 6)      asm volatile("s_waitcnt vmcnt(2)" ::: "memory");
    else if (c < 7) asm volatile("s_waitcnt vmcnt(1)" ::: "memory");
    else            asm volatile("s_waitcnt vmcnt(0)" ::: "memory");
    __builtin_amdgcn_s_barrier();
    __builtin_amdgcn_sched_barrier(0);
    // stage c+3 into the buffer all waves finished reading at iter c-1.
    if (c < 5) stage(c + 3, (c + 3) & 3);
    int buf = c & 3;

    f32x4 acc[2];
    acc[0] = (f32x4){0.f, 0.f, 0.f, 0.f};
    acc[1] = (f32x4){0.f, 0.f, 0.f, 0.f};
    __builtin_amdgcn_s_setprio(1);
#pragma unroll
    for (int ks = 0; ks < 4; ++ks) {
      int kir = kg * 16 + l15;
      int off = kir * DK + (((l4 + 4 * ks) ^ l15) << 3);
      short8v bh = *(const short8v*)(&klds[buf][off]);
#pragma unroll
      for (int mt = 0; mt < 2; ++mt)
        acc[mt] = __builtin_amdgcn_mfma_f32_16x16x32_bf16(ah[ks][mt], bh, acc[mt], 0, 0, 0);
    }
    __builtin_amdgcn_s_setprio(0);

    // fold chunk scores into per-lane running top-3 (index in low 8 bits)
    unsigned idx = (unsigned)(c * 32 + kg * 16 + l15);
#pragma unroll
    for (int mt = 0; mt < 2; ++mt)
#pragma unroll
      for (int r = 0; r < 4; ++r) {
        float p = __uint_as_float((__float_as_uint(acc[mt][r]) & 0xFFFFFF00u) | idx);
        ins3(p, rv1[mt][r], rv2[mt][r], rv3[mt][r]);
      }
  }

  // butterfly-merge top-3 across the 16 key-lanes (once per block)
#pragma unroll
  for (int mt = 0; mt < 2; ++mt)
#pragma unroll
    for (int r = 0; r < 4; ++r) {
      float v1 = rv1[mt][r], v2 = rv2[mt][r], v3 = rv3[mt][r];
#pragma unroll
      for (int s = 1; s < 16; s <<= 1) {
        float w1 = __shfl_xor(v1, s, 16);
        float w2 = __shfl_xor(v2, s, 16);
        float w3 = __shfl_xor(v3, s, 16);
        ins3(w1, v1, v2, v3);
        ins3(w2, v1, v2, v3);
        ins3(w3, v1, v2, v3);
      }
      if (l15 == 0) {
        int mloc = (mg * 2 + mt) * 16 + l4 * 4 + r;
        mbuf[mloc][kg * 3]     = v1;
        mbuf[mloc][kg * 3 + 1] = v2;
        mbuf[mloc][kg * 3 + 2] = v3;
      }
    }
  __syncthreads();

  if (tid < 128) {
    float v1 = mbuf[tid][0], v2 = mbuf[tid][1], v3 = mbuf[tid][2];
    ins3(mbuf[tid][3], v1, v2, v3);
    ins3(mbuf[tid][4], v1, v2, v3);
    ins3(mbuf[tid][5], v1, v2, v3);
    size_t o = (size_t)row * N_ + Q * 128 + tid;  // [row][mention], coalesced
    rmax1[o] = v1;
    rmax2[o] = v2;
    rmax3[o] = v3;
  }
}

// ---------------------------------------------------------------------------
// Kernel 3: per-mention exact selection (f64 rescoring), softmax, pooling.
// rmax arrays are [row][mention]; key indices live in score low 8 bits.
// Row ranking via 512-element bitonic sort (val desc, row asc) - exact ties.
// Candidate cap 96 (window EPS2 below approx rank-32).
// ---------------------------------------------------------------------------
__global__ __launch_bounds__(256) void k_select(
    const double* __restrict__ qf64, const float* __restrict__ keys,
    const float* __restrict__ rmax1, const float* __restrict__ rmax2,
    const float* __restrict__ rmax3,
    const int* __restrict__ memmask, const int* __restrict__ eids,
    const float* __restrict__ mvals,
    float* __restrict__ out_w, float* __restrict__ out_ids,
    float* __restrict__ pooled) {
  int m = blockIdx.x, tid = threadIdx.x;
  __shared__ double q_d[DK];
  __shared__ float  vals[NROWS];
  __shared__ unsigned long long skey[NROWS];
  __shared__ int    slotRow[CCAP];
  __shared__ float  slotV[CCAP];
  __shared__ double cval[CCAP];
  __shared__ int    carg[CCAP];
  __shared__ float  Tsh;
  __shared__ int    Csh;
  __shared__ int    fgid[KTOP];
  __shared__ double fval[KTOP];
  __shared__ float  wsm[KTOP];

  for (int i = tid; i < DK; i += 256) q_d[i] = qf64[(size_t)m * DK + i];
  for (int i = tid; i < NROWS; i += 256) {
    float v = rmax1[(size_t)i * N_ + m];
    vals[i] = v;
    unsigned u = __float_as_uint(v);
    unsigned ordv = (u & 0x80000000u) ? ~u : (u | 0x80000000u);  // asc order
    skey[i] = ((unsigned long long)(~ordv) << 32) | (unsigned)i; // desc, row asc
  }
  __syncthreads();

  // bitonic sort 512 keys ascending => val desc, row asc
  for (int k = 2; k <= NROWS; k <<= 1) {
    for (int j = k >> 1; j > 0; j >>= 1) {
      for (int i = tid; i < NROWS; i += 256) {
        int p = i ^ j;
        if (p > i) {
          bool up = ((i & k) == 0);
          unsigned long long a = skey[i], b = skey[p];
          if ((a > b) == up) { skey[i] = b; skey[p] = a; }
        }
      }
      __syncthreads();
    }
  }

  if (tid < CCAP) {
    int r = (int)(skey[tid] & 0xFFFFFFFFu);
    slotRow[tid] = r;
    slotV[tid] = vals[r];
  }
  __syncthreads();
  if (tid == 0) {
    Tsh = slotV[KTOP - 1] - EPS2;
    int C = KTOP;
    while (C < CCAP && slotV[C] >= Tsh) ++C;
    Csh = C;
  }
  __syncthreads();
  int C = Csh;

  // f64 rescore candidates: top-1 always; top-2/3 if within EPS2 of top-1
  if (tid < C) {
    int row = slotRow[tid];
    size_t o = (size_t)row * N_ + m;
    float v1 = vals[row], v2 = rmax2[o], v3 = rmax3[o];
    int i1 = (int)(__float_as_uint(v1) & 0xFFu);
    int i2 = (int)(__float_as_uint(v2) & 0xFFu);
    int i3 = (int)(__float_as_uint(v3) & 0xFFu);
    const float* kp = keys + ((size_t)row * VPR + i1) * DK;
    double s1 = 0.0;
    for (int d = 0; d < DK; ++d) s1 += q_d[d] * (double)kp[d];
    double val = s1; int arg = i1;
    if (v1 - v2 <= EPS2) {
      const float* kp2 = keys + ((size_t)row * VPR + i2) * DK;
      double s2 = 0.0;
      for (int d = 0; d < DK; ++d) s2 += q_d[d] * (double)kp2[d];
      if (s2 > val || (s2 == val && i2 < arg)) { val = s2; arg = i2; }
    }
    if (v1 - v3 <= EPS2) {
      const float* kp3 = keys + ((size_t)row * VPR + i3) * DK;
      double s3 = 0.0;
      for (int d = 0; d < DK; ++d) s3 += q_d[d] * (double)kp3[d];
      if (s3 > val || (s3 == val && i3 < arg)) { val = s3; arg = i3; }
    }
    cval[tid] = val; carg[tid] = arg;
  }
  __syncthreads();

  // exact top-32 among candidates (value desc, row asc)
  if (tid < C) {
    double v = cval[tid]; int row = slotRow[tid]; int rank = 0;
    for (int j = 0; j < C; ++j) {
      double u = cval[j]; int rj = slotRow[j];
      rank += (u > v) | ((u == v) & (rj < row));
    }
    if (rank < KTOP) { fgid[rank] = row * VPR + carg[tid]; fval[rank] = v; }
  }
  __syncthreads();

  if (tid < KTOP) {
    int gid = fgid[tid];
    double sc = fval[tid] - (1.0 - (double)memmask[gid]) * 1e10;
    double mx = sc;
#pragma unroll
    for (int off = 16; off >= 1; off >>= 1) mx = fmax(mx, __shfl_xor(mx, off, 32));
    double e = exp(sc - mx), ss = e;
#pragma unroll
    for (int off = 16; off >= 1; off >>= 1) ss += __shfl_xor(ss, off, 32);
    float w = (float)(e / ss);
    out_w[(size_t)m * KTOP + tid] = w;
    out_ids[(size_t)m * KTOP + tid] = (float)eids[gid];
    wsm[tid] = w;
  }
  __syncthreads();

  for (int d = tid; d < DV; d += 256) {
    float acc = 0.f;
#pragma unroll 8
    for (int i = 0; i < KTOP; ++i) acc += wsm[i] * mvals[(size_t)fgid[i] * DV + d];
    pooled[(size_t)m * DV + d] = acc;
  }
}

// ---------------------------------------------------------------------------
// Kernel 4: projected = pooled @ update_w + b, * mention_mask, scatter-add.
// ---------------------------------------------------------------------------
__global__ __launch_bounds__(256) void k_project(
    const float* __restrict__ pooled, const float* __restrict__ uw,
    const float* __restrict__ ub, const float* __restrict__ mmsk,
    const int* __restrict__ mbp, const int* __restrict__ msp,
    float* __restrict__ delta) {
  int mt = blockIdx.x, tid = threadIdx.x;
  __shared__ float p_s[4 * DV];
  for (int i = tid; i < 4 * DV; i += 256) p_s[i] = pooled[(size_t)mt * 4 * DV + i];
  __syncthreads();
  float a0[4] = {}, a1[4] = {}, a2[4] = {};
  for (int d = 0; d < DV; ++d) {
    float w0 = uw[(size_t)d * H_ + tid];
    float w1 = uw[(size_t)d * H_ + tid + 256];
    float w2 = uw[(size_t)d * H_ + tid + 512];
#pragma unroll
    for (int q = 0; q < 4; ++q) {
      float p = p_s[q * DV + d];
      a0[q] += p * w0; a1[q] += p * w1; a2[q] += p * w2;
    }
  }
#pragma unroll
  for (int q = 0; q < 4; ++q) {
    int m = mt * 4 + q;
    float msk = mmsk[m];
    float* dst = delta + ((size_t)(mbp[m] * T_ + msp[m])) * H_;
    atomicAdd(dst + tid,       (a0[q] + ub[tid])       * msk);
    atomicAdd(dst + tid + 256, (a1[q] + ub[tid + 256]) * msk);
    atomicAdd(dst + tid + 512, (a2[q] + ub[tid + 512]) * msk);
  }
}

// ---------------------------------------------------------------------------
// Kernel 5: LayerNorm over H for every (b,t), reading enc + delta.
// ---------------------------------------------------------------------------
__device__ __forceinline__ float blockReduceSum(float v, float* red, int tid) {
#pragma unroll
  for (int off = 32; off >= 1; off >>= 1) v += __shfl_xor(v, off, 64);
  __syncthreads();
  if ((tid & 63) == 0) red[tid >> 6] = v;
  __syncthreads();
  return red[0] + red[1] + red[2] + red[3];
}

__global__ __launch_bounds__(256) void k_ln(
    const float* __restrict__ enc, const float* __restrict__ delta,
    const float* __restrict__ lns, const float* __restrict__ lnb,
    float* __restrict__ out) {
  int r = blockIdx.x, tid = threadIdx.x;
  size_t base = (size_t)r * H_;
  __shared__ float red[4];
  float x0 = enc[base + tid]       + delta[base + tid];
  float x1 = enc[base + tid + 256] + delta[base + tid + 256];
  float x2 = enc[base + tid + 512] + delta[base + tid + 512];
  float mu = blockReduceSum(x0 + x1 + x2, red, tid) * (1.f / 768.f);
  float d0 = x0 - mu, d1 = x1 - mu, d2 = x2 - mu;
  float var = blockReduceSum(d0 * d0 + d1 * d1 + d2 * d2, red, tid) * (1.f / 768.f);
  float rs = 1.f / sqrtf(var + 1e-12f);
  out[base + tid]       = d0 * rs * lns[tid]       + lnb[tid];
  out[base + tid + 256] = d1 * rs * lns[tid + 256] + lnb[tid + 256];
  out[base + tid + 512] = d2 * rs * lns[tid + 512] + lnb[tid + 512];
}

// ---------------------------------------------------------------------------
extern "C" void kernel_launch(void* const* d_in, const int* in_sizes, int n_in,
                              void* d_out, int out_size, void* d_ws, size_t ws_size,
                              hipStream_t stream) {
  (void)in_sizes; (void)n_in; (void)out_size; (void)ws_size;
  const float* enc     = (const float*)d_in[0];
  const int*   mbp     = (const int*)d_in[1];
  const int*   msp     = (const int*)d_in[2];
  const int*   mep     = (const int*)d_in[3];
  const float* mmsk    = (const float*)d_in[4];
  const float* keys    = (const float*)d_in[5];
  const float* mvals   = (const float*)d_in[6];
  const int*   memmask = (const int*)d_in[7];
  const int*   eids    = (const int*)d_in[8];
  const float* qw      = (const float*)d_in[9];
  const float* qb      = (const float*)d_in[10];
  const float* uw      = (const float*)d_in[11];
  const float* ub      = (const float*)d_in[12];
  const float* lns     = (const float*)d_in[13];
  const float* lnb     = (const float*)d_in[14];

  char* ws = (char*)d_ws;
  double*         qf64   = (double*)(ws + WS_QF64);
  unsigned short* qhi    = (unsigned short*)(ws + WS_QHI);
  float*          rmax1  = (float*)(ws + WS_RMAX1);
  float*          rmax2  = (float*)(ws + WS_RMAX2);
  float*          rmax3  = (float*)(ws + WS_RMAX3);
  float*          pooled = (float*)(ws + WS_POOLED);
  float*          delta  = (float*)(ws + WS_DELTA);
  unsigned short* khi    = (unsigned short*)(ws + WS_KHI);

  float* out_enc = (float*)d_out;
  float* out_w   = out_enc + (size_t)B_ * T_ * H_;
  float* out_ids = out_w + (size_t)N_ * KTOP;

  k_zero<<<(B_ * T_ * H_) / 1024, 256, 0, stream>>>((float4*)delta);
  k_split<<<M_ / 16, 256, 0, stream>>>(keys, khi);
  k_queries<<<N_ / 4, 512, 0, stream>>>(enc, mbp, msp, mep, qw, qb, qf64, qhi);
  // TIMING INSTRUMENT (round 14): k_score launched twice. It is a pure
  // function of (khi,qhi) -> (rmax1..3); the duplicate writes identical
  // values. Total-time delta vs round 13 == T(k_score) under graph replay.
  k_score<<<NROWS * 8, 512, 0, stream>>>(khi, qhi, rmax1, rmax2, rmax3);
  k_score<<<NROWS * 8, 512, 0, stream>>>(khi, qhi, rmax1, rmax2, rmax3);
  k_select<<<N_, 256, 0, stream>>>(qf64, keys, rmax1, rmax2, rmax3,
                                   memmask, eids, mvals, out_w, out_ids, pooled);
  k_project<<<N_ / 4, 256, 0, stream>>>(pooled, uw, ub, mmsk, mbp, msp, delta);
  k_ln<<<B_ * T_, 256, 0, stream>>>(enc, delta, lns, lnb, out_enc);
}

// Round 15
// 193.376 us; speedup vs baseline: 1.6357x; 1.6357x over previous
//
#include <hip/hip_runtime.h>
#include <math.h>

#define B_ 32
#define T_ 128
#define H_ 768
#define N_ 1024
#define M_ 131072
#define DK 128
#define DV 512
#define NROWS 512
#define VPR 256
#define KTOP 32
#define EPS2 1.2f   // 2.7x the 2-sided hard error bound of 1-pass bf16 scoring
#define CCAP 96

typedef __attribute__((ext_vector_type(8))) short short8v;
typedef __attribute__((ext_vector_type(4))) float f32x4;

// ---- workspace layout (bytes) ----
#define WS_QF64   ((size_t)0)
#define WS_QHI    (WS_QF64 + (size_t)N_*DK*8)
#define WS_RMAX1  (WS_QHI + (size_t)N_*DK*2)
#define WS_RMAX2  (WS_RMAX1 + (size_t)N_*NROWS*4)
#define WS_RMAX3  (WS_RMAX2 + (size_t)N_*NROWS*4)
#define WS_POOLED (WS_RMAX3 + (size_t)N_*NROWS*4)
#define WS_DELTA  (WS_POOLED + (size_t)N_*DV*4)
// total ~22 MB

__device__ __forceinline__ unsigned short bf16_rn(float x) {
  unsigned u = __float_as_uint(x);
  unsigned r = u + 0x7FFFu + ((u >> 16) & 1u);
  return (unsigned short)(r >> 16);
}

// top-3 insert: 5 ops, exact (values are distinct via packed index bits)
__device__ __forceinline__ void ins3(float p, float& v1, float& v2, float& v3) {
  float m1 = fminf(v1, p);
  v1 = fmaxf(v1, p);
  float m2 = fminf(v2, m1);
  v2 = fmaxf(v2, m1);
  v3 = fmaxf(v3, m2);
}

// ---------------------------------------------------------------------------
// Kernel 1: queries (f64 acc), 4 mentions per block (qw reuse x4).
// Also zero-fills delta (fused former k_zero: 256 blocks x 512 thr x 6 f4).
// Writes qf64 + fragment-ordered bf16 hi pack.
// ---------------------------------------------------------------------------
__global__ __launch_bounds__(512) void k_queries(
    const float* __restrict__ enc, const int* __restrict__ mbp,
    const int* __restrict__ msp, const int* __restrict__ mep,
    const float* __restrict__ qw, const float* __restrict__ qb,
    double* __restrict__ qf64, unsigned short* __restrict__ qhi,
    float4* __restrict__ delta4) {
  int g = blockIdx.x, t = threadIdx.x;
  {
    size_t zb = (size_t)g * 3072 + t;   // 256*512*6 = 786432 = delta float4s
#pragma unroll
    for (int j = 0; j < 6; ++j) delta4[zb + j * 512] = (float4){0.f, 0.f, 0.f, 0.f};
  }
  int d = t & 127, qq = t >> 7;   // quarter 0..3
  __shared__ float se[4][H_], ee[4][H_];
  __shared__ double part[4][512];
#pragma unroll
  for (int mm = 0; mm < 4; ++mm) {
    int m = g * 4 + mm;
    int b = mbp[m], s = msp[m], e = mep[m];
    const float* rs = enc + ((size_t)(b * T_ + s)) * H_;
    const float* re = enc + ((size_t)(b * T_ + e)) * H_;
    for (int h = t; h < H_; h += 512) { se[mm][h] = rs[h]; ee[mm][h] = re[h]; }
  }
  __syncthreads();
  int h0 = (qq & 1) * 384;
  int wbase = (qq >> 1) * H_ + h0;
  double acc0 = 0, acc1 = 0, acc2 = 0, acc3 = 0;
  if (qq < 2) {
    for (int h = 0; h < 384; ++h) {
      double w = (double)qw[(size_t)(wbase + h) * DK + d];
      acc0 += (double)se[0][h0 + h] * w; acc1 += (double)se[1][h0 + h] * w;
      acc2 += (double)se[2][h0 + h] * w; acc3 += (double)se[3][h0 + h] * w;
    }
  } else {
    for (int h = 0; h < 384; ++h) {
      double w = (double)qw[(size_t)(wbase + h) * DK + d];
      acc0 += (double)ee[0][h0 + h] * w; acc1 += (double)ee[1][h0 + h] * w;
      acc2 += (double)ee[2][h0 + h] * w; acc3 += (double)ee[3][h0 + h] * w;
    }
  }
  part[0][t] = acc0; part[1][t] = acc1; part[2][t] = acc2; part[3][t] = acc3;
  __syncthreads();
  {
    int mm = t >> 7, dd = t & 127;
    int m = g * 4 + mm;
    double v = (double)qb[dd] + part[mm][dd] + part[mm][dd + 128] +
               part[mm][dd + 256] + part[mm][dd + 384];
    qf64[(size_t)m * DK + dd] = v;
    unsigned hv = bf16_rn((float)v);
    int mtg = m >> 4, r16 = m & 15, ks = dd >> 5, sub = (dd >> 3) & 3;
    size_t idx = ((size_t)(mtg * 4 + ks) * 64 + sub * 16 + r16) * 8 + (dd & 7);
    qhi[idx] = (unsigned short)hv;
  }
}

// ---------------------------------------------------------------------------
// Kernel 2: 1-pass bf16 MFMA scoring, SWAPPED operands (A=keys, B=queries):
// output row=key, col=mention -> per-lane top-3 fold is IN-LANE over 32 key
// scores (kt x r); cross-lane merge is only xor16+xor32 (12 shuffles/wave/Q
// vs 96 before). Persistent-row blocks: grid=512 (one row each); the row's
// 256 keys are converted f32->bf16 ONCE into the swizzled 64 KB LDS image,
// then 8 Q-tiles (128 mentions each) compute with keys LDS-resident.
// Replaces the former k_split pass entirely. Output [row][mention].
// ---------------------------------------------------------------------------
__global__ __launch_bounds__(512, 4) void k_score(
    const float* __restrict__ keys, const unsigned short* __restrict__ qhi,
    float* __restrict__ rmax1, float* __restrict__ rmax2,
    float* __restrict__ rmax3) {
  __shared__ unsigned short klds[VPR * DK];   // 64 KB swizzled bf16 key image
  __shared__ float mbuf[128][6];              // 3 KB
  int row = blockIdx.x;
  int tid = threadIdx.x;
  int lane = tid & 63, wave = tid >> 6;
  int mg = wave >> 1, kg = wave & 1;
  int l15 = lane & 15, l4 = lane >> 4;

  // ---- stage: convert this row's keys once (thread = half a key) ----
  {
    int key = tid >> 1, half = tid & 1;
    const float* src = keys + ((size_t)row * VPR + key) * DK + half * 64;
    int swz = key & 15;
#pragma unroll
    for (int j = 0; j < 8; ++j) {          // dim granule half*8+j (8 dims)
      float4 fa = *(const float4*)(src + j * 8);
      float4 fb = *(const float4*)(src + j * 8 + 4);
      unsigned h0 = (unsigned)bf16_rn(fa.x) | ((unsigned)bf16_rn(fa.y) << 16);
      unsigned h1 = (unsigned)bf16_rn(fa.z) | ((unsigned)bf16_rn(fa.w) << 16);
      unsigned h2 = (unsigned)bf16_rn(fb.x) | ((unsigned)bf16_rn(fb.y) << 16);
      unsigned h3 = (unsigned)bf16_rn(fb.z) | ((unsigned)bf16_rn(fb.w) << 16);
      int gg = (half * 8 + j) ^ swz;
      uint4 u = {h0, h1, h2, h3};
      *(uint4*)(&klds[key * DK + (gg << 3)]) = u;
    }
  }
  __syncthreads();

  for (int Q = 0; Q < 8; ++Q) {
    // B-fragments (queries) for this wave's 2 mention-subtiles
    short8v bq[4][2];
#pragma unroll
    for (int ks = 0; ks < 4; ++ks)
#pragma unroll
      for (int mt = 0; mt < 2; ++mt) {
        int mtg = Q * 8 + mg * 2 + mt;
        size_t aoff = ((size_t)(mtg * 4 + ks) * 64 + lane) * 8;
        bq[ks][mt] = *(const short8v*)(qhi + aoff);
      }

    float rv1[2], rv2[2], rv3[2];
#pragma unroll
    for (int mt = 0; mt < 2; ++mt) {
      rv1[mt] = -INFINITY; rv2[mt] = -INFINITY; rv3[mt] = -INFINITY;
    }

#pragma unroll
    for (int kt = 0; kt < 8; ++kt) {
      f32x4 acc[2];
      acc[0] = (f32x4){0.f, 0.f, 0.f, 0.f};
      acc[1] = (f32x4){0.f, 0.f, 0.f, 0.f};
#pragma unroll
      for (int ks = 0; ks < 4; ++ks) {
        int kir = kg * 128 + kt * 16 + l15;
        int off = kir * DK + (((l4 + 4 * ks) ^ l15) << 3);
        short8v ak = *(const short8v*)(&klds[off]);
        acc[0] = __builtin_amdgcn_mfma_f32_16x16x32_bf16(ak, bq[ks][0], acc[0], 0, 0, 0);
        acc[1] = __builtin_amdgcn_mfma_f32_16x16x32_bf16(ak, bq[ks][1], acc[1], 0, 0, 0);
      }
      // swapped output: row=key = kg*128+kt*16+l4*4+r, col=mention=l15.
      // fold in-lane (no cross-lane): 8 values per kt into per-mt top-3.
#pragma unroll
      for (int mt = 0; mt < 2; ++mt)
#pragma unroll
        for (int r = 0; r < 4; ++r) {
          unsigned kidx = (unsigned)(kg * 128 + kt * 16 + l4 * 4 + r);
          float p = __uint_as_float((__float_as_uint(acc[mt][r]) & 0xFFFFFF00u) | kidx);
          ins3(p, rv1[mt], rv2[mt], rv3[mt]);
        }
    }

    // merge across the 4 l4-lanes holding the same mention (xor 16, 32)
#pragma unroll
    for (int mt = 0; mt < 2; ++mt) {
      float v1 = rv1[mt], v2 = rv2[mt], v3 = rv3[mt];
#pragma unroll
      for (int s = 16; s <= 32; s <<= 1) {
        float w1 = __shfl_xor(v1, s, 64);
        float w2 = __shfl_xor(v2, s, 64);
        float w3 = __shfl_xor(v3, s, 64);
        ins3(w1, v1, v2, v3);
        ins3(w2, v1, v2, v3);
        ins3(w3, v1, v2, v3);
      }
      if (l4 == 0) {
        int mloc = mg * 32 + mt * 16 + l15;
        mbuf[mloc][kg * 3]     = v1;
        mbuf[mloc][kg * 3 + 1] = v2;
        mbuf[mloc][kg * 3 + 2] = v3;
      }
    }
    __syncthreads();

    if (tid < 128) {
      float v1 = mbuf[tid][0], v2 = mbuf[tid][1], v3 = mbuf[tid][2];
      ins3(mbuf[tid][3], v1, v2, v3);
      ins3(mbuf[tid][4], v1, v2, v3);
      ins3(mbuf[tid][5], v1, v2, v3);
      size_t o = (size_t)row * N_ + Q * 128 + tid;  // [row][mention]
      rmax1[o] = v1;
      rmax2[o] = v2;
      rmax3[o] = v3;
    }
    __syncthreads();   // mbuf free for next Q
  }
}

// ---------------------------------------------------------------------------
// Kernel 3: per-mention exact selection (f64 rescoring), softmax, pooling.
// rmax arrays are [row][mention]; key indices live in score low 8 bits.
// Row ranking via 512-element bitonic sort (val desc, row asc) - exact ties.
// Candidate cap 96 (window EPS2 below approx rank-32).
// ---------------------------------------------------------------------------
__global__ __launch_bounds__(256) void k_select(
    const double* __restrict__ qf64, const float* __restrict__ keys,
    const float* __restrict__ rmax1, const float* __restrict__ rmax2,
    const float* __restrict__ rmax3,
    const int* __restrict__ memmask, const int* __restrict__ eids,
    const float* __restrict__ mvals,
    float* __restrict__ out_w, float* __restrict__ out_ids,
    float* __restrict__ pooled) {
  int m = blockIdx.x, tid = threadIdx.x;
  __shared__ double q_d[DK];
  __shared__ float  vals[NROWS];
  __shared__ unsigned long long skey[NROWS];
  __shared__ int    slotRow[CCAP];
  __shared__ float  slotV[CCAP];
  __shared__ double cval[CCAP];
  __shared__ int    carg[CCAP];
  __shared__ float  Tsh;
  __shared__ int    Csh;
  __shared__ int    fgid[KTOP];
  __shared__ double fval[KTOP];
  __shared__ float  wsm[KTOP];

  for (int i = tid; i < DK; i += 256) q_d[i] = qf64[(size_t)m * DK + i];
  for (int i = tid; i < NROWS; i += 256) {
    float v = rmax1[(size_t)i * N_ + m];
    vals[i] = v;
    unsigned u = __float_as_uint(v);
    unsigned ordv = (u & 0x80000000u) ? ~u : (u | 0x80000000u);  // asc order
    skey[i] = ((unsigned long long)(~ordv) << 32) | (unsigned)i; // desc, row asc
  }
  __syncthreads();

  // bitonic sort 512 keys ascending => val desc, row asc
  for (int k = 2; k <= NROWS; k <<= 1) {
    for (int j = k >> 1; j > 0; j >>= 1) {
      for (int i = tid; i < NROWS; i += 256) {
        int p = i ^ j;
        if (p > i) {
          bool up = ((i & k) == 0);
          unsigned long long a = skey[i], b = skey[p];
          if ((a > b) == up) { skey[i] = b; skey[p] = a; }
        }
      }
      __syncthreads();
    }
  }

  if (tid < CCAP) {
    int r = (int)(skey[tid] & 0xFFFFFFFFu);
    slotRow[tid] = r;
    slotV[tid] = vals[r];
  }
  __syncthreads();
  if (tid == 0) {
    Tsh = slotV[KTOP - 1] - EPS2;
    int C = KTOP;
    while (C < CCAP && slotV[C] >= Tsh) ++C;
    Csh = C;
  }
  __syncthreads();
  int C = Csh;

  // f64 rescore candidates: top-1 always; top-2/3 if within EPS2 of top-1
  if (tid < C) {
    int row = slotRow[tid];
    size_t o = (size_t)row * N_ + m;
    float v1 = vals[row], v2 = rmax2[o], v3 = rmax3[o];
    int i1 = (int)(__float_as_uint(v1) & 0xFFu);
    int i2 = (int)(__float_as_uint(v2) & 0xFFu);
    int i3 = (int)(__float_as_uint(v3) & 0xFFu);
    const float* kp = keys + ((size_t)row * VPR + i1) * DK;
    double s1 = 0.0;
    for (int d = 0; d < DK; ++d) s1 += q_d[d] * (double)kp[d];
    double val = s1; int arg = i1;
    if (v1 - v2 <= EPS2) {
      const float* kp2 = keys + ((size_t)row * VPR + i2) * DK;
      double s2 = 0.0;
      for (int d = 0; d < DK; ++d) s2 += q_d[d] * (double)kp2[d];
      if (s2 > val || (s2 == val && i2 < arg)) { val = s2; arg = i2; }
    }
    if (v1 - v3 <= EPS2) {
      const float* kp3 = keys + ((size_t)row * VPR + i3) * DK;
      double s3 = 0.0;
      for (int d = 0; d < DK; ++d) s3 += q_d[d] * (double)kp3[d];
      if (s3 > val || (s3 == val && i3 < arg)) { val = s3; arg = i3; }
    }
    cval[tid] = val; carg[tid] = arg;
  }
  __syncthreads();

  // exact top-32 among candidates (value desc, row asc)
  if (tid < C) {
    double v = cval[tid]; int row = slotRow[tid]; int rank = 0;
    for (int j = 0; j < C; ++j) {
      double u = cval[j]; int rj = slotRow[j];
      rank += (u > v) | ((u == v) & (rj < row));
    }
    if (rank < KTOP) { fgid[rank] = row * VPR + carg[tid]; fval[rank] = v; }
  }
  __syncthreads();

  if (tid < KTOP) {
    int gid = fgid[tid];
    double sc = fval[tid] - (1.0 - (double)memmask[gid]) * 1e10;
    double mx = sc;
#pragma unroll
    for (int off = 16; off >= 1; off >>= 1) mx = fmax(mx, __shfl_xor(mx, off, 32));
    double e = exp(sc - mx), ss = e;
#pragma unroll
    for (int off = 16; off >= 1; off >>= 1) ss += __shfl_xor(ss, off, 32);
    float w = (float)(e / ss);
    out_w[(size_t)m * KTOP + tid] = w;
    out_ids[(size_t)m * KTOP + tid] = (float)eids[gid];
    wsm[tid] = w;
  }
  __syncthreads();

  for (int d = tid; d < DV; d += 256) {
    float acc = 0.f;
#pragma unroll 8
    for (int i = 0; i < KTOP; ++i) acc += wsm[i] * mvals[(size_t)fgid[i] * DV + d];
    pooled[(size_t)m * DV + d] = acc;
  }
}

// ---------------------------------------------------------------------------
// Kernel 4: projected = pooled @ update_w + b, * mention_mask, scatter-add.
// ---------------------------------------------------------------------------
__global__ __launch_bounds__(256) void k_project(
    const float* __restrict__ pooled, const float* __restrict__ uw,
    const float* __restrict__ ub, const float* __restrict__ mmsk,
    const int* __restrict__ mbp, const int* __restrict__ msp,
    float* __restrict__ delta) {
  int mt = blockIdx.x, tid = threadIdx.x;
  __shared__ float p_s[4 * DV];
  for (int i = tid; i < 4 * DV; i += 256) p_s[i] = pooled[(size_t)mt * 4 * DV + i];
  __syncthreads();
  float a0[4] = {}, a1[4] = {}, a2[4] = {};
  for (int d = 0; d < DV; ++d) {
    float w0 = uw[(size_t)d * H_ + tid];
    float w1 = uw[(size_t)d * H_ + tid + 256];
    float w2 = uw[(size_t)d * H_ + tid + 512];
#pragma unroll
    for (int q = 0; q < 4; ++q) {
      float p = p_s[q * DV + d];
      a0[q] += p * w0; a1[q] += p * w1; a2[q] += p * w2;
    }
  }
#pragma unroll
  for (int q = 0; q < 4; ++q) {
    int m = mt * 4 + q;
    float msk = mmsk[m];
    float* dst = delta + ((size_t)(mbp[m] * T_ + msp[m])) * H_;
    atomicAdd(dst + tid,       (a0[q] + ub[tid])       * msk);
    atomicAdd(dst + tid + 256, (a1[q] + ub[tid + 256]) * msk);
    atomicAdd(dst + tid + 512, (a2[q] + ub[tid + 512]) * msk);
  }
}

// ---------------------------------------------------------------------------
// Kernel 5: LayerNorm over H for every (b,t), reading enc + delta.
// ---------------------------------------------------------------------------
__device__ __forceinline__ float blockReduceSum(float v, float* red, int tid) {
#pragma unroll
  for (int off = 32; off >= 1; off >>= 1) v += __shfl_xor(v, off, 64);
  __syncthreads();
  if ((tid & 63) == 0) red[tid >> 6] = v;
  __syncthreads();
  return red[0] + red[1] + red[2] + red[3];
}

__global__ __launch_bounds__(256) void k_ln(
    const float* __restrict__ enc, const float* __restrict__ delta,
    const float* __restrict__ lns, const float* __restrict__ lnb,
    float* __restrict__ out) {
  int r = blockIdx.x, tid = threadIdx.x;
  size_t base = (size_t)r * H_;
  __shared__ float red[4];
  float x0 = enc[base + tid]       + delta[base + tid];
  float x1 = enc[base + tid + 256] + delta[base + tid + 256];
  float x2 = enc[base + tid + 512] + delta[base + tid + 512];
  float mu = blockReduceSum(x0 + x1 + x2, red, tid) * (1.f / 768.f);
  float d0 = x0 - mu, d1 = x1 - mu, d2 = x2 - mu;
  float var = blockReduceSum(d0 * d0 + d1 * d1 + d2 * d2, red, tid) * (1.f / 768.f);
  float rs = 1.f / sqrtf(var + 1e-12f);
  out[base + tid]       = d0 * rs * lns[tid]       + lnb[tid];
  out[base + tid + 256] = d1 * rs * lns[tid + 256] + lnb[tid + 256];
  out[base + tid + 512] = d2 * rs * lns[tid + 512] + lnb[tid + 512];
}

// ---------------------------------------------------------------------------
extern "C" void kernel_launch(void* const* d_in, const int* in_sizes, int n_in,
                              void* d_out, int out_size, void* d_ws, size_t ws_size,
                              hipStream_t stream) {
  (void)in_sizes; (void)n_in; (void)out_size; (void)ws_size;
  const float* enc     = (const float*)d_in[0];
  const int*   mbp     = (const int*)d_in[1];
  const int*   msp     = (const int*)d_in[2];
  const int*   mep     = (const int*)d_in[3];
  const float* mmsk    = (const float*)d_in[4];
  const float* keys    = (const float*)d_in[5];
  const float* mvals   = (const float*)d_in[6];
  const int*   memmask = (const int*)d_in[7];
  const int*   eids    = (const int*)d_in[8];
  const float* qw      = (const float*)d_in[9];
  const float* qb      = (const float*)d_in[10];
  const float* uw      = (const float*)d_in[11];
  const float* ub      = (const float*)d_in[12];
  const float* lns     = (const float*)d_in[13];
  const float* lnb     = (const float*)d_in[14];

  char* ws = (char*)d_ws;
  double*         qf64   = (double*)(ws + WS_QF64);
  unsigned short* qhi    = (unsigned short*)(ws + WS_QHI);
  float*          rmax1  = (float*)(ws + WS_RMAX1);
  float*          rmax2  = (float*)(ws + WS_RMAX2);
  float*          rmax3  = (float*)(ws + WS_RMAX3);
  float*          pooled = (float*)(ws + WS_POOLED);
  float*          delta  = (float*)(ws + WS_DELTA);

  float* out_enc = (float*)d_out;
  float* out_w   = out_enc + (size_t)B_ * T_ * H_;
  float* out_ids = out_w + (size_t)N_ * KTOP;

  k_queries<<<N_ / 4, 512, 0, stream>>>(enc, mbp, msp, mep, qw, qb, qf64, qhi,
                                        (float4*)delta);
  k_score<<<NROWS, 512, 0, stream>>>(keys, qhi, rmax1, rmax2, rmax3);
  k_select<<<N_, 256, 0, stream>>>(qf64, keys, rmax1, rmax2, rmax3,
                                   memmask, eids, mvals, out_w, out_ids, pooled);
  k_project<<<N_ / 4, 256, 0, stream>>>(pooled, uw, ub, mmsk, mbp, msp, delta);
  k_ln<<<B_ * T_, 256, 0, stream>>>(enc, delta, lns, lnb, out_enc);
}